// Round 6
// baseline (269.224 us; speedup 1.0000x reference)
//
#include <hip/hip_runtime.h>

#define D_MODEL 128
#define HIDDEN 64

// pool kernel: zero LDS, full occupancy
#define P_WPB 4
#define P_NTHREADS 256
#define P_NBLOCKS 2048        // 8192 waves; 8 blocks/CU -> 32 waves/CU

// mlp kernel
#define M_WPB 8
#define M_NTHREADS 512
#define M_NBLOCKS 512
#define W1_STRIDE 132         // 128 + 4 pad
#define W2_STRIDE 68          // 64 + 4 pad
#define SEG_BATCH 4

// Kernel 1: segment start offsets from sorted segment_ids.
__global__ void seg_bounds_kernel(const int* __restrict__ seg, int n, int B,
                                  int* __restrict__ seg_start) {
  int i = blockIdx.x * blockDim.x + threadIdx.x;
  if (i >= n) return;
  int s = seg[i];
  if (i == 0) {
    for (int t = 0; t <= s; ++t) seg_start[t] = 0;
  } else {
    int p = seg[i - 1];
    for (int t = p + 1; t <= s; ++t) seg_start[t] = i;
  }
  if (i == n - 1) {
    for (int t = s + 1; t <= B; ++t) seg_start[t] = n;
  }
}

__device__ __forceinline__ float silu(float x) {
  return x / (1.0f + __expf(-x));
}
__device__ __forceinline__ float4 f4add(float4 a, float4 b) {
  return make_float4(a.x + b.x, a.y + b.y, a.z + b.z, a.w + b.w);
}
__device__ __forceinline__ float wave_sum(float p) {
#pragma unroll
  for (int off = 32; off >= 1; off >>= 1) p += __shfl_xor(p, off);
  return p;
}
// smallest s in [0, B] with arr[s] >= target (arr nondecreasing, arr[B]=n)
__device__ __forceinline__ int lower_bound_ge(const int* __restrict__ arr,
                                              int B, int target) {
  int lo = 0, hi = B;
  while (lo < hi) {
    int m = (lo + hi) >> 1;
    if (arr[m] >= target) hi = m; else lo = m + 1;
  }
  return lo;
}

// Kernel 2: PURE STREAMING pool. One wave per atom-balanced contiguous chunk
// (segment owned by the wave whose atom-window contains its start -> no
// atomics, no overlap). Writes per-segment MEANS to pooled[B][128].
// Zero LDS, ~32 VGPR -> 32 waves/CU.
__global__ __launch_bounds__(P_NTHREADS, 8) void pool_kernel(
    const float* __restrict__ h, const int* __restrict__ seg_start,
    float* __restrict__ pooled, int B, int n_atoms) {
  const int wave = threadIdx.x >> 6;
  const int lane = threadIdx.x & 63;
  const int G = gridDim.x * P_WPB;
  const int g = blockIdx.x * P_WPB + wave;
  const int lo = (int)(((long long)g * n_atoms) / G);
  const int hi = (int)(((long long)(g + 1) * n_atoms) / G);
  const int my_s0 = lower_bound_ge(seg_start, B, lo);
  const int s_end = (g == G - 1) ? B : lower_bound_ge(seg_start, B, hi);
  if (s_end <= my_s0) return;

  const int half = lane >> 5;   // lanes 0..31 even atoms, 32..63 odd atoms
  const int l32 = lane & 31;
  const float4* __restrict__ hv = reinterpret_cast<const float4*>(h);
  float4* __restrict__ pooledv = reinterpret_cast<float4*>(pooled);

  int start = seg_start[my_s0];
  for (int s = my_s0; s < s_end; ++s) {
    const int end = seg_start[s + 1];
    const int cnt = end - start;
    // round-3's proven 2-deep loop (best measured streaming structure)
    float4 acc0 = make_float4(0.f, 0.f, 0.f, 0.f);
    float4 acc1 = acc0;
    int a = start + half;
    for (; a + 2 < end; a += 4) {
      float4 v0 = hv[a * 32 + l32];
      float4 v1 = hv[(a + 2) * 32 + l32];
      acc0 = f4add(acc0, v0);
      acc1 = f4add(acc1, v1);
    }
    if (a < end) {
      float4 v0 = hv[a * 32 + l32];
      acc0 = f4add(acc0, v0);
    }
    acc0 = f4add(acc0, acc1);
    acc0.x += __shfl_xor(acc0.x, 32);
    acc0.y += __shfl_xor(acc0.y, 32);
    acc0.z += __shfl_xor(acc0.z, 32);
    acc0.w += __shfl_xor(acc0.w, 32);
    const float inv = 1.0f / (float)max(cnt, 1);
    if (half == 0) {
      pooledv[s * 32 + l32] = make_float4(acc0.x * inv, acc0.y * inv,
                                          acc0.z * inv, acc0.w * inv);
    }
    start = end;  // contiguous chunk
  }
}

// Kernel 3: batched MLP over pooled means (grid-stride; 4 segments per wave
// pass; weights staged once per block into transposed/padded LDS).
__global__ __launch_bounds__(M_NTHREADS, 4) void mlp_kernel(
    const float* __restrict__ pooled,
    const float* __restrict__ W1, const float* __restrict__ b1,
    const float* __restrict__ W2, const float* __restrict__ b2,
    const float* __restrict__ W3, const float* __restrict__ b3,
    float* __restrict__ out, int B) {
  __shared__ float sW1T[HIDDEN * W1_STRIDE];              // 33.0 KB
  __shared__ float sW2T[HIDDEN * W2_STRIDE];              // 17.0 KB
  __shared__ float pooled_lds[M_WPB][SEG_BATCH][D_MODEL]; // 16 KB
  __shared__ float x1_lds[M_WPB][SEG_BATCH][HIDDEN];      // 8 KB

  const int tid = threadIdx.x;
#pragma unroll
  for (int i = tid; i < (D_MODEL * HIDDEN) / 4; i += M_NTHREADS) {
    float4 v = reinterpret_cast<const float4*>(W1)[i];
    int k = i >> 4;
    int j = (4 * i) & (HIDDEN - 1);
    sW1T[(j + 0) * W1_STRIDE + k] = v.x;
    sW1T[(j + 1) * W1_STRIDE + k] = v.y;
    sW1T[(j + 2) * W1_STRIDE + k] = v.z;
    sW1T[(j + 3) * W1_STRIDE + k] = v.w;
  }
#pragma unroll
  for (int i = tid; i < (HIDDEN * HIDDEN) / 4; i += M_NTHREADS) {
    float4 v = reinterpret_cast<const float4*>(W2)[i];
    int k = i >> 4;
    int j = (4 * i) & (HIDDEN - 1);
    sW2T[(j + 0) * W2_STRIDE + k] = v.x;
    sW2T[(j + 1) * W2_STRIDE + k] = v.y;
    sW2T[(j + 2) * W2_STRIDE + k] = v.z;
    sW2T[(j + 3) * W2_STRIDE + k] = v.w;
  }
  __syncthreads();

  const int wave = tid >> 6;
  const int lane = tid & 63;
  const int half = lane >> 5;
  const int l32 = lane & 31;
  const float b1l = b1[lane];
  const float b2l = b2[lane];
  const float w3l = W3[lane];
  const float b3l = b3[0];

  const float4* __restrict__ pooledv = reinterpret_cast<const float4*>(pooled);
  const float4* __restrict__ w1v =
      reinterpret_cast<const float4*>(&sW1T[lane * W1_STRIDE]);
  const float4* __restrict__ w2v =
      reinterpret_cast<const float4*>(&sW2T[lane * W2_STRIDE]);

  const int GW = gridDim.x * M_WPB;
  const int nbatch = (B + SEG_BATCH - 1) / SEG_BATCH;
  for (int batch = blockIdx.x * M_WPB + wave; batch < nbatch; batch += GW) {
    const int s0 = batch * SEG_BATCH;
    const int nb = min(SEG_BATCH, B - s0);

    // stage 4 pooled vectors (coalesced float4; 2 segments per pass)
#pragma unroll
    for (int b = 0; b < SEG_BATCH; b += 2) {
      const int bb = b + half;
      const int sb = s0 + min(bb, nb - 1);
      reinterpret_cast<float4*>(&pooled_lds[wave][bb][0])[l32] =
          pooledv[sb * 32 + l32];
    }
    __builtin_amdgcn_wave_barrier();

    const float4* pv0 = reinterpret_cast<const float4*>(&pooled_lds[wave][0][0]);
    const float4* pv1 = reinterpret_cast<const float4*>(&pooled_lds[wave][1][0]);
    const float4* pv2 = reinterpret_cast<const float4*>(&pooled_lds[wave][2][0]);
    const float4* pv3 = reinterpret_cast<const float4*>(&pooled_lds[wave][3][0]);
    float a1b0 = b1l, a1b1 = b1l, a1b2 = b1l, a1b3 = b1l;
#pragma unroll 8
    for (int t = 0; t < D_MODEL / 4; ++t) {
      float4 w = w1v[t];
      float4 p0 = pv0[t], p1 = pv1[t], p2 = pv2[t], p3 = pv3[t];
      a1b0 = fmaf(p0.x, w.x, a1b0); a1b0 = fmaf(p0.y, w.y, a1b0);
      a1b0 = fmaf(p0.z, w.z, a1b0); a1b0 = fmaf(p0.w, w.w, a1b0);
      a1b1 = fmaf(p1.x, w.x, a1b1); a1b1 = fmaf(p1.y, w.y, a1b1);
      a1b1 = fmaf(p1.z, w.z, a1b1); a1b1 = fmaf(p1.w, w.w, a1b1);
      a1b2 = fmaf(p2.x, w.x, a1b2); a1b2 = fmaf(p2.y, w.y, a1b2);
      a1b2 = fmaf(p2.z, w.z, a1b2); a1b2 = fmaf(p2.w, w.w, a1b2);
      a1b3 = fmaf(p3.x, w.x, a1b3); a1b3 = fmaf(p3.y, w.y, a1b3);
      a1b3 = fmaf(p3.z, w.z, a1b3); a1b3 = fmaf(p3.w, w.w, a1b3);
    }
    x1_lds[wave][0][lane] = silu(a1b0);
    x1_lds[wave][1][lane] = silu(a1b1);
    x1_lds[wave][2][lane] = silu(a1b2);
    x1_lds[wave][3][lane] = silu(a1b3);
    __builtin_amdgcn_wave_barrier();

    const float4* x10 = reinterpret_cast<const float4*>(&x1_lds[wave][0][0]);
    const float4* x11 = reinterpret_cast<const float4*>(&x1_lds[wave][1][0]);
    const float4* x12 = reinterpret_cast<const float4*>(&x1_lds[wave][2][0]);
    const float4* x13 = reinterpret_cast<const float4*>(&x1_lds[wave][3][0]);
    float a2b0 = b2l, a2b1 = b2l, a2b2 = b2l, a2b3 = b2l;
#pragma unroll 8
    for (int t = 0; t < HIDDEN / 4; ++t) {
      float4 w = w2v[t];
      float4 p0 = x10[t], p1 = x11[t], p2 = x12[t], p3 = x13[t];
      a2b0 = fmaf(p0.x, w.x, a2b0); a2b0 = fmaf(p0.y, w.y, a2b0);
      a2b0 = fmaf(p0.z, w.z, a2b0); a2b0 = fmaf(p0.w, w.w, a2b0);
      a2b1 = fmaf(p1.x, w.x, a2b1); a2b1 = fmaf(p1.y, w.y, a2b1);
      a2b1 = fmaf(p1.z, w.z, a2b1); a2b1 = fmaf(p1.w, w.w, a2b1);
      a2b2 = fmaf(p2.x, w.x, a2b2); a2b2 = fmaf(p2.y, w.y, a2b2);
      a2b2 = fmaf(p2.z, w.z, a2b2); a2b2 = fmaf(p2.w, w.w, a2b2);
      a2b3 = fmaf(p3.x, w.x, a2b3); a2b3 = fmaf(p3.y, w.y, a2b3);
      a2b3 = fmaf(p3.z, w.z, a2b3); a2b3 = fmaf(p3.w, w.w, a2b3);
    }
    float r0 = wave_sum(silu(a2b0) * w3l);
    float r1 = wave_sum(silu(a2b1) * w3l);
    float r2 = wave_sum(silu(a2b2) * w3l);
    float r3 = wave_sum(silu(a2b3) * w3l);
    float val = (lane == 0) ? r0 : (lane == 1) ? r1 : (lane == 2) ? r2 : r3;
    if (lane < nb) out[s0 + lane] = val + b3l;
  }
}

extern "C" void kernel_launch(void* const* d_in, const int* in_sizes, int n_in,
                              void* d_out, int out_size, void* d_ws, size_t ws_size,
                              hipStream_t stream) {
  const float* h = (const float*)d_in[0];
  const int* seg = (const int*)d_in[1];
  // d_in[2] = num_segments (device scalar; use out_size instead — host-known)
  const float* W1 = (const float*)d_in[3];
  const float* b1 = (const float*)d_in[4];
  const float* W2 = (const float*)d_in[5];
  const float* b2 = (const float*)d_in[6];
  const float* W3 = (const float*)d_in[7];
  const float* b3 = (const float*)d_in[8];
  float* out = (float*)d_out;

  const int n = in_sizes[1];      // number of atoms
  const int B = out_size;         // number of segments

  // workspace layout: seg_start (B+1 ints), then pooled (B*128 floats, 16B-aligned)
  int* seg_start = (int*)d_ws;
  size_t pooled_off = ((size_t)(B + 1) * sizeof(int) + 255) & ~(size_t)255;
  float* pooled = (float*)((char*)d_ws + pooled_off);

  {
    int threads = 256;
    int blocks = (n + threads - 1) / threads;
    seg_bounds_kernel<<<blocks, threads, 0, stream>>>(seg, n, B, seg_start);
  }
  pool_kernel<<<P_NBLOCKS, P_NTHREADS, 0, stream>>>(h, seg_start, pooled, B, n);
  mlp_kernel<<<M_NBLOCKS, M_NTHREADS, 0, stream>>>(
      pooled, W1, b1, W2, b2, W3, b3, out, B);
}

// Round 7
// 169.838 us; speedup vs baseline: 1.5852x; 1.5852x over previous
//
#include <hip/hip_runtime.h>

#define D_MODEL 128
#define HIDDEN 64
#define WPB 8                 // waves per block
#define NTHREADS (WPB * 64)
#define NBLOCKS 512           // persistent: 2 blocks/CU on 256 CUs
#define W1_STRIDE 132         // 128 + 4 pad (float4-aligned, spreads banks)
#define W2_STRIDE 68          // 64 + 4 pad

typedef float f4_t __attribute__((ext_vector_type(4)));

// Kernel 1: segment start offsets from sorted segment_ids.
// seg_start has B+1 entries; segment s spans [seg_start[s], seg_start[s+1]).
__global__ void seg_bounds_kernel(const int* __restrict__ seg, int n, int B,
                                  int* __restrict__ seg_start) {
  int i = blockIdx.x * blockDim.x + threadIdx.x;
  if (i >= n) return;
  int s = seg[i];
  if (i == 0) {
    for (int t = 0; t <= s; ++t) seg_start[t] = 0;
  } else {
    int p = seg[i - 1];
    for (int t = p + 1; t <= s; ++t) seg_start[t] = i;
  }
  if (i == n - 1) {
    for (int t = s + 1; t <= B; ++t) seg_start[t] = n;
  }
}

__device__ __forceinline__ float silu(float x) {
  return x / (1.0f + __expf(-x));
}

// Kernel 2 (R3 structure, proven 197us): persistent waves, contiguous
// count-balanced segment chunks, per-segment pool + MLP from LDS-transposed
// weights. Single change vs R3: nontemporal loads for the h stream (zero
// reuse -> bypass L2 allocate).
__global__ __launch_bounds__(NTHREADS, 4) void pool_mlp_kernel(
    const float* __restrict__ h, const int* __restrict__ seg_start,
    const float* __restrict__ W1, const float* __restrict__ b1,
    const float* __restrict__ W2, const float* __restrict__ b2,
    const float* __restrict__ W3, const float* __restrict__ b3,
    float* __restrict__ out, int B) {
  __shared__ float sW1T[HIDDEN * W1_STRIDE];  // W1^T padded: [j][k] 33.8 KB
  __shared__ float sW2T[HIDDEN * W2_STRIDE];  // W2^T padded: [j][k] 17.4 KB
  __shared__ float pooled_lds[WPB][D_MODEL];  // 4 KB
  __shared__ float x1_lds[WPB][HIDDEN];       // 2 KB

  const int tid = threadIdx.x;

  // ---- one-time staging: W1 (k,j) -> sW1T[j*W1_STRIDE + k], same for W2.
#pragma unroll
  for (int i = tid; i < (D_MODEL * HIDDEN) / 4; i += NTHREADS) {
    float4 v = reinterpret_cast<const float4*>(W1)[i];
    int k = i >> 4;            // 16 float4 per k-row (HIDDEN=64)
    int j = (4 * i) & (HIDDEN - 1);
    sW1T[(j + 0) * W1_STRIDE + k] = v.x;
    sW1T[(j + 1) * W1_STRIDE + k] = v.y;
    sW1T[(j + 2) * W1_STRIDE + k] = v.z;
    sW1T[(j + 3) * W1_STRIDE + k] = v.w;
  }
#pragma unroll
  for (int i = tid; i < (HIDDEN * HIDDEN) / 4; i += NTHREADS) {
    float4 v = reinterpret_cast<const float4*>(W2)[i];
    int k = i >> 4;
    int j = (4 * i) & (HIDDEN - 1);
    sW2T[(j + 0) * W2_STRIDE + k] = v.x;
    sW2T[(j + 1) * W2_STRIDE + k] = v.y;
    sW2T[(j + 2) * W2_STRIDE + k] = v.z;
    sW2T[(j + 3) * W2_STRIDE + k] = v.w;
  }
  __syncthreads();  // only barrier in the kernel

  const int wave = tid >> 6;
  const int lane = tid & 63;

  // per-wave-constant params in registers (amortized over the chunk)
  const float b1l = b1[lane];
  const float b2l = b2[lane];
  const float w3l = W3[lane];
  const float b3l = b3[0];

  // ---- balanced contiguous chunk assignment (by segment count; R3-proven)
  const int G = gridDim.x * WPB;              // total waves
  const int g = blockIdx.x * WPB + wave;
  const int base = B / G;
  const int rem = B - base * G;
  const int my_cnt = base + (g < rem ? 1 : 0);
  const int my_s0 = g * base + (g < rem ? g : rem);
  if (my_cnt == 0) return;

  const int half = lane >> 5;   // lanes 0..31 even atoms, 32..63 odd atoms
  const int l32 = lane & 31;
  const f4_t* __restrict__ hv = reinterpret_cast<const f4_t*>(h);
  const float4* __restrict__ pv =
      reinterpret_cast<const float4*>(&pooled_lds[wave][0]);
  const float4* __restrict__ x1v =
      reinterpret_cast<const float4*>(&x1_lds[wave][0]);
  const float4* __restrict__ w1v =
      reinterpret_cast<const float4*>(&sW1T[lane * W1_STRIDE]);
  const float4* __restrict__ w2v =
      reinterpret_cast<const float4*>(&sW2T[lane * W2_STRIDE]);

  int start = seg_start[my_s0];
  for (int si = 0; si < my_cnt; ++si) {
    const int s = my_s0 + si;
    const int end = seg_start[s + 1];
    const int cnt = end - start;

    // ---- pooling: lanes 0..31 = even atom's 128 floats, lanes 32..63 = odd
    // atom -> each wave instr loads 1KB contiguous. 2x unrolled, nontemporal.
    f4_t acc0 = {0.f, 0.f, 0.f, 0.f};
    f4_t acc1 = {0.f, 0.f, 0.f, 0.f};
    int a = start + half;
    for (; a + 2 < end; a += 4) {
      f4_t v0 = __builtin_nontemporal_load(&hv[a * 32 + l32]);
      f4_t v1 = __builtin_nontemporal_load(&hv[(a + 2) * 32 + l32]);
      acc0 += v0;
      acc1 += v1;
    }
    if (a < end) {
      f4_t v0 = __builtin_nontemporal_load(&hv[a * 32 + l32]);
      acc0 += v0;
    }
    acc0 += acc1;
    acc0[0] += __shfl_xor(acc0[0], 32);
    acc0[1] += __shfl_xor(acc0[1], 32);
    acc0[2] += __shfl_xor(acc0[2], 32);
    acc0[3] += __shfl_xor(acc0[3], 32);

    const float inv = 1.0f / (float)max(cnt, 1);
    if (half == 0) {
      float4 p = make_float4(acc0[0] * inv, acc0[1] * inv,
                             acc0[2] * inv, acc0[3] * inv);
      reinterpret_cast<float4*>(&pooled_lds[wave][0])[l32] = p;
    }
    __builtin_amdgcn_wave_barrier();  // wave64 lockstep; waitcnt orders LDS

    // ---- layer 1: lane j = hidden unit j; broadcast pooled float4 +
    // contiguous W1^T row float4 (b128 reads, bank-phase optimal)
    float a1 = b1l;
#pragma unroll 8
    for (int t = 0; t < D_MODEL / 4; ++t) {
      float4 p = pv[t];
      float4 w = w1v[t];
      a1 = fmaf(p.x, w.x, a1);
      a1 = fmaf(p.y, w.y, a1);
      a1 = fmaf(p.z, w.z, a1);
      a1 = fmaf(p.w, w.w, a1);
    }
    const float x1 = silu(a1);
    x1_lds[wave][lane] = x1;
    __builtin_amdgcn_wave_barrier();

    // ---- layer 2
    float a2 = b2l;
#pragma unroll 8
    for (int t = 0; t < HIDDEN / 4; ++t) {
      float4 p = x1v[t];
      float4 w = w2v[t];
      a2 = fmaf(p.x, w.x, a2);
      a2 = fmaf(p.y, w.y, a2);
      a2 = fmaf(p.z, w.z, a2);
      a2 = fmaf(p.w, w.w, a2);
    }
    const float x2 = silu(a2);

    // ---- layer 3: dot(x2, W3) shuffle reduce
    float prod = x2 * w3l;
#pragma unroll
    for (int off = 32; off >= 1; off >>= 1) {
      prod += __shfl_xor(prod, off);
    }
    if (lane == 0) out[s] = prod + b3l;

    start = end;  // contiguous chunk: next segment starts where this ended
  }
}

extern "C" void kernel_launch(void* const* d_in, const int* in_sizes, int n_in,
                              void* d_out, int out_size, void* d_ws, size_t ws_size,
                              hipStream_t stream) {
  const float* h = (const float*)d_in[0];
  const int* seg = (const int*)d_in[1];
  // d_in[2] = num_segments (device scalar; use out_size instead — host-known)
  const float* W1 = (const float*)d_in[3];
  const float* b1 = (const float*)d_in[4];
  const float* W2 = (const float*)d_in[5];
  const float* b2 = (const float*)d_in[6];
  const float* W3 = (const float*)d_in[7];
  const float* b3 = (const float*)d_in[8];
  float* out = (float*)d_out;

  const int n = in_sizes[1];      // number of atoms
  const int B = out_size;         // number of segments

  int* seg_start = (int*)d_ws;    // B+1 ints

  {
    int threads = 256;
    int blocks = (n + threads - 1) / threads;
    seg_bounds_kernel<<<blocks, threads, 0, stream>>>(seg, n, B, seg_start);
  }
  {
    pool_mlp_kernel<<<NBLOCKS, NTHREADS, 0, stream>>>(
        h, seg_start, W1, b1, W2, b2, W3, b3, out, B);
  }
}